// Round 1
// baseline (3334.162 us; speedup 1.0000x reference)
//
#include <hip/hip_runtime.h>
#include <hip/hip_bf16.h>

// B=8192, T=32, D_IN=2, EMB=128, H=256, 4H=1024
// Fused: embed(relu) + 2-layer LSTM, all 32 steps in one kernel.
// 256 blocks x 256 threads; block owns 32 batch rows; wave w owns
// e-slice [64w,64w+64) of all 4 gates (cols 256q+64w+16s+cc).
// MFMA 16x16x32 bf16, swapped operands: D = z^T tile, batch row in lane&15.

typedef __attribute__((ext_vector_type(8))) __bf16 bf16x8;
typedef __attribute__((ext_vector_type(4))) __bf16 bf16x4;
typedef __attribute__((ext_vector_type(4))) float f32x4;

#define MFMA16(a, b, c) __builtin_amdgcn_mfma_f32_16x16x32_bf16(a, b, c, 0, 0, 0)

__device__ __forceinline__ float fexp2(float x) {
#if __has_builtin(__builtin_amdgcn_exp2f)
  return __builtin_amdgcn_exp2f(x);
#else
  return exp2f(x);
#endif
}
__device__ __forceinline__ float frcp(float x) {
#if __has_builtin(__builtin_amdgcn_rcpf)
  return __builtin_amdgcn_rcpf(x);
#else
  return 1.0f / x;
#endif
}
__device__ __forceinline__ float fsig(float x) {
  return frcp(1.0f + fexp2(-1.44269504f * x));
}
__device__ __forceinline__ float ftanh(float x) {
  return 1.0f - 2.0f * frcp(1.0f + fexp2(2.88539008f * x));
}

// ---- weight prep: swizzle [W;U] (K x 1024) fp32 into per-frag bf16 order ----
// layer0: frag index g = (w*16+ct)*12 + kc   (K=384, kc=0..11)
// element: k = 32*kc + (l>>4)*8 + j ; c = 256*(ct>>2) + 64*w + 16*(ct&3) + (l&15)
__global__ void prep_w0(const float* __restrict__ W0, const float* __restrict__ U0,
                        __bf16* __restrict__ o) {
  const int f = blockIdx.x * 256 + threadIdx.x;  // < 393216
  const int j = f & 7, l5 = (f >> 3) & 63, g = f >> 9;
  const int kc = g % 12, ct = (g / 12) & 15, w = g / 192;
  const int k = (kc << 5) + ((l5 >> 4) << 3) + j;
  const int c = ((ct >> 2) << 8) + (w << 6) + ((ct & 3) << 4) + (l5 & 15);
  const float v = (k < 128) ? W0[(k << 10) + c] : U0[((k - 128) << 10) + c];
  o[f] = (__bf16)v;
}
// layer1: frag index g = ((w*2+hf)*16+ct)*8 + kc  (K=512, two halves of 8 kc)
__global__ void prep_w1(const float* __restrict__ W1, const float* __restrict__ U1,
                        __bf16* __restrict__ o) {
  const int f = blockIdx.x * 256 + threadIdx.x;  // < 524288
  const int j = f & 7, l5 = (f >> 3) & 63, g = f >> 9;
  const int kc = g & 7, ct = (g >> 3) & 15, hf = (g >> 7) & 1, w = g >> 8;
  const int k = (((hf << 3) + kc) << 5) + ((l5 >> 4) << 3) + j;
  const int c = ((ct >> 2) << 8) + (w << 6) + ((ct & 3) << 4) + (l5 & 15);
  const float v = (k < 256) ? W1[(k << 10) + c] : U1[((k - 256) << 10) + c];
  o[f] = (__bf16)v;
}

__global__ __launch_bounds__(256, 1)
void lstm_fused(const float* __restrict__ traj,
                const float* __restrict__ Wemb,
                const float* __restrict__ bemb,
                const float* __restrict__ bias0,
                const float* __restrict__ bias1,
                const __bf16* __restrict__ wb0,
                const __bf16* __restrict__ wb1,
                float* __restrict__ out) {
  __shared__ float s_We[384];        // We[0][0:128], We[1][0:128], be[0:128]
  __shared__ float s_b[2][1024];     // bias arranged per (w,ct,cc)
  __shared__ float s_traj[2048];     // [r][t][2]
  __shared__ __bf16 s_h0[2][8192];   // [buf][r*256 + (e ^ ((r&7)<<3))]
  __shared__ __bf16 s_h1[2][8192];

  const int tid = threadIdx.x;
  const int w = tid >> 6;
  const int l = tid & 63;
  const int lr = l & 15;
  const int lg = l >> 4;
  const int xr = (lr & 7) << 3;      // swizzle mask (element space), fn of row only
  const int r0 = blockIdx.x << 5;

  for (int i = tid; i < 384; i += 256) s_We[i] = (i < 256) ? Wemb[i] : bemb[i - 256];
  for (int i = tid; i < 1024; i += 256) {
    const int ww = i >> 8, ct = (i >> 4) & 15, cc = i & 15;
    const int col = ((ct >> 2) << 8) + (ww << 6) + ((ct & 3) << 4) + cc;
    s_b[0][i] = bias0[col];
    s_b[1][i] = bias1[col];
  }
  for (int i = tid; i < 2048; i += 256) s_traj[i] = traj[(r0 << 6) + i];
  for (int i = tid; i < 8192; i += 256) {
    s_h0[0][i] = (__bf16)0.f;
    s_h1[0][i] = (__bf16)0.f;
  }
  __syncthreads();

  float c0[2][4][4] = {};
  float c1[2][4][4] = {};

  const __bf16* wp0 = wb0 + (w * 192) * 512 + l * 8;
  const __bf16* wp1 = wb1 + (w * 256) * 512 + l * 8;

#pragma unroll 1
  for (int t = 0; t < 32; ++t) {
    const int cur = t & 1, nxt = cur ^ 1;

    {  // ------------- layer 0: z = [x_t | h0] @ [W0;U0] + b0 -------------
      bf16x8 ina[2][12];
#pragma unroll
      for (int rt = 0; rt < 2; ++rt) {
        const int r = (rt << 4) + lr;
        const float t0 = s_traj[(r << 6) + (t << 1)];
        const float t1 = s_traj[(r << 6) + (t << 1) + 1];
#pragma unroll
        for (int kc = 0; kc < 4; ++kc) {  // x part: computed on the fly
          bf16x8 v;
#pragma unroll
          for (int j = 0; j < 8; ++j) {
            const int k = (kc << 5) + (lg << 3) + j;
            const float x = fmaf(t0, s_We[k], fmaf(t1, s_We[128 + k], s_We[256 + k]));
            v[j] = (__bf16)fmaxf(x, 0.f);
          }
          ina[rt][kc] = v;
        }
#pragma unroll
        for (int kc = 0; kc < 8; ++kc) {  // h0 part from LDS
          const int idx = (r << 8) + ((((kc << 5) + (lg << 3))) ^ xr);
          ina[rt][4 + kc] = *reinterpret_cast<const bf16x8*>(&s_h0[cur][idx]);
        }
      }
      f32x4 acc[16][2];
#pragma unroll
      for (int ct = 0; ct < 16; ++ct) {
        const f32x4 b = *reinterpret_cast<const f32x4*>(
            &s_b[0][(((w << 4) + ct) << 4) + (lg << 2)]);
        acc[ct][0] = b;
        acc[ct][1] = b;
      }
#pragma unroll
      for (int ct = 0; ct < 16; ++ct) {
#pragma unroll
        for (int kc = 0; kc < 12; ++kc) {
          const bf16x8 wf = *reinterpret_cast<const bf16x8*>(wp0 + (ct * 12 + kc) * 512);
          acc[ct][0] = MFMA16(wf, ina[0][kc], acc[ct][0]);
          acc[ct][1] = MFMA16(wf, ina[1][kc], acc[ct][1]);
        }
      }
#pragma unroll
      for (int rt = 0; rt < 2; ++rt) {
        const int r = (rt << 4) + lr;
#pragma unroll
        for (int s = 0; s < 4; ++s) {
          bf16x4 hv;
          f32x4 hf, cf;
#pragma unroll
          for (int i = 0; i < 4; ++i) {
            const float zi = acc[s][rt][i];
            const float zf = acc[4 + s][rt][i];
            const float zg = acc[8 + s][rt][i];
            const float zo = acc[12 + s][rt][i];
            const float cc = fsig(zf) * c0[rt][s][i] + fsig(zi) * ftanh(zg);
            c0[rt][s][i] = cc;
            const float hh = fsig(zo) * ftanh(cc);
            hv[i] = (__bf16)hh;
            hf[i] = hh;
            cf[i] = cc;
          }
          const int e0 = (w << 6) + (s << 4) + (lg << 2);
          const int idx = (r << 8) + (e0 ^ xr);
          *reinterpret_cast<bf16x4*>(&s_h0[nxt][idx]) = hv;
          if (t == 31) {
            const int base = ((r0 + r) << 8) + e0;
            *reinterpret_cast<f32x4*>(out + 67108864 + base) = hf;  // h0 final
            *reinterpret_cast<f32x4*>(out + 69206016 + base) = cf;  // c0 final
          }
        }
      }
    }
    __syncthreads();

    {  // ------------- layer 1: z = [h0_new | h1] @ [W1;U1] + b1 -------------
      f32x4 acc[16][2];
#pragma unroll
      for (int ct = 0; ct < 16; ++ct) {
        const f32x4 b = *reinterpret_cast<const f32x4*>(
            &s_b[1][(((w << 4) + ct) << 4) + (lg << 2)]);
        acc[ct][0] = b;
        acc[ct][1] = b;
      }
#pragma unroll
      for (int hf2 = 0; hf2 < 2; ++hf2) {
        bf16x8 inb[2][8];
        const __bf16* src = hf2 ? s_h1[cur] : s_h0[nxt];
#pragma unroll
        for (int rt = 0; rt < 2; ++rt) {
          const int r = (rt << 4) + lr;
#pragma unroll
          for (int kc = 0; kc < 8; ++kc) {
            const int idx = (r << 8) + ((((kc << 5) + (lg << 3))) ^ xr);
            inb[rt][kc] = *reinterpret_cast<const bf16x8*>(&src[idx]);
          }
        }
#pragma unroll
        for (int ct = 0; ct < 16; ++ct) {
#pragma unroll
          for (int kc = 0; kc < 8; ++kc) {
            const bf16x8 wf = *reinterpret_cast<const bf16x8*>(
                wp1 + ((hf2 << 7) + (ct << 3) + kc) * 512);
            acc[ct][0] = MFMA16(wf, inb[0][kc], acc[ct][0]);
            acc[ct][1] = MFMA16(wf, inb[1][kc], acc[ct][1]);
          }
        }
      }
#pragma unroll
      for (int rt = 0; rt < 2; ++rt) {
        const int r = (rt << 4) + lr;
#pragma unroll
        for (int s = 0; s < 4; ++s) {
          bf16x4 hv;
          f32x4 hf, cf;
#pragma unroll
          for (int i = 0; i < 4; ++i) {
            const float zi = acc[s][rt][i];
            const float zf = acc[4 + s][rt][i];
            const float zg = acc[8 + s][rt][i];
            const float zo = acc[12 + s][rt][i];
            const float cc = fsig(zf) * c1[rt][s][i] + fsig(zi) * ftanh(zg);
            c1[rt][s][i] = cc;
            const float hh = fsig(zo) * ftanh(cc);
            hv[i] = (__bf16)hh;
            hf[i] = hh;
            cf[i] = cc;
          }
          const int e0 = (w << 6) + (s << 4) + (lg << 2);
          const int idx = (r << 8) + (e0 ^ xr);
          *reinterpret_cast<bf16x4*>(&s_h1[nxt][idx]) = hv;
          // y1[b][t][e]
          *reinterpret_cast<f32x4*>(out + ((((r0 + r) << 5) + t) << 8) + e0) = hf;
          if (t == 31) {
            const int base = ((r0 + r) << 8) + e0;
            *reinterpret_cast<f32x4*>(out + 71303168 + base) = hf;  // h1 final
            *reinterpret_cast<f32x4*>(out + 73400320 + base) = cf;  // c1 final
          }
        }
      }
    }
    __syncthreads();
  }
}

extern "C" void kernel_launch(void* const* d_in, const int* in_sizes, int n_in,
                              void* d_out, int out_size, void* d_ws, size_t ws_size,
                              hipStream_t stream) {
  const float* traj = (const float*)d_in[0];
  const float* Wemb = (const float*)d_in[1];
  const float* bemb = (const float*)d_in[2];
  const float* W0 = (const float*)d_in[3];
  const float* U0 = (const float*)d_in[4];
  const float* b0 = (const float*)d_in[5];
  const float* W1 = (const float*)d_in[6];
  const float* U1 = (const float*)d_in[7];
  const float* b1 = (const float*)d_in[8];
  float* out = (float*)d_out;

  __bf16* wb0 = (__bf16*)d_ws;          // 393216 elems = 768 KB
  __bf16* wb1 = wb0 + 393216;           // 524288 elems = 1 MB

  hipLaunchKernelGGL(prep_w0, dim3(1536), dim3(256), 0, stream, W0, U0, wb0);
  hipLaunchKernelGGL(prep_w1, dim3(2048), dim3(256), 0, stream, W1, U1, wb1);
  hipLaunchKernelGGL(lstm_fused, dim3(256), dim3(256), 0, stream,
                     traj, Wemb, bemb, b0, b1, wb0, wb1, out);
}